// Round 2
// baseline (1562.554 us; speedup 1.0000x reference)
//
#include <hip/hip_runtime.h>

#define NN 10000
#define NE 160000
#define ROWU 2112          // uints per node row (4224 bf16 = 66*64)
#define OUTSTRIDE 640000   // N*O floats per batch image

typedef unsigned int uint;
typedef unsigned short ushort;
typedef __attribute__((ext_vector_type(8))) short short8;
typedef __attribute__((ext_vector_type(4))) float f32x4;

__device__ __forceinline__ float bflo(uint u) { return __uint_as_float(u << 16); }
__device__ __forceinline__ float bfhi(uint u) { return __uint_as_float(u & 0xffff0000u); }
// RTNE pack of two fp32 -> packed bf16 pair
__device__ __forceinline__ uint packbf(float a, float b) {
    uint ua = __float_as_uint(a); ua += 0x7fffu + ((ua >> 16) & 1u);
    uint ub = __float_as_uint(b); ub += 0x7fffu + ((ub >> 16) & 1u);
    return (ua >> 16) | (ub & 0xffff0000u);
}

// ---------- x0[n][b*66+d] (bf16) = inputs[b][n*66+d] ----------
__global__ __launch_bounds__(256) void transpose_kernel(const float* __restrict__ in,
                                                        uint* __restrict__ x0) {
    const int n = blockIdx.x, t = threadIdx.x;
    const float* src = in + (size_t)n * 66;
    uint* dst = x0 + (size_t)n * ROWU;
#pragma unroll
    for (int j = 0; j < 9; j++) {
        const int ui = 256 * j + t;
        if (ui < ROWU) {
            const int idx = 2 * ui;                 // element index b*66+d (even, so no b-cross)
            const int b = (int)(((long long)idx * 63551) >> 22);   // idx/66
            const int d = idx - 66 * b;
            const float a0 = src[(size_t)b * 660000 + d];
            const float a1 = src[(size_t)b * 660000 + d + 1];
            dst[ui] = packbf(a0, a1);
        }
    }
}

// ---------- CSR build (both supports in one dispatch each) ----------
__global__ __launch_bounds__(256) void hist_kernel(const int* __restrict__ r0,
                                                   const int* __restrict__ r1,
                                                   int* __restrict__ c0,
                                                   int* __restrict__ c1) {
    const int bid = blockIdx.x;
    const bool sB = bid >= (NE / 256);
    const int e = (sB ? bid - NE / 256 : bid) * 256 + threadIdx.x;
    const int* rows = sB ? r1 : r0;
    int* cnt = sB ? c1 : c0;
    atomicAdd(&cnt[rows[e]], 1);
}

__global__ __launch_bounds__(1024) void scan_kernel(const int* __restrict__ c0,
                                                    int* __restrict__ rp0_, int* __restrict__ cur0_,
                                                    const int* __restrict__ c1,
                                                    int* __restrict__ rp1_, int* __restrict__ cur1_) {
    const int s = blockIdx.x;
    const int* cnt = s ? c1 : c0;
    int* rp  = s ? rp1_  : rp0_;
    int* cur = s ? cur1_ : cur0_;
    __shared__ int sums[1024];
    const int t = threadIdx.x;
    const int base = t * 10;
    int vals[10];
    int local = 0;
#pragma unroll
    for (int i = 0; i < 10; i++) {
        const int idx = base + i;
        const int v = (idx < NN) ? cnt[idx] : 0;
        vals[i] = local;
        local += v;
    }
    sums[t] = local;
    __syncthreads();
    for (int off = 1; off < 1024; off <<= 1) {
        const int v = (t >= off) ? sums[t - off] : 0;
        __syncthreads();
        sums[t] += v;
        __syncthreads();
    }
    const int excl = (t == 0) ? 0 : sums[t - 1];
#pragma unroll
    for (int i = 0; i < 10; i++) {
        const int idx = base + i;
        if (idx < NN) {
            const int v = excl + vals[i];
            rp[idx] = v;
            cur[idx] = v;
        }
    }
    if (t == 1023) rp[NN] = sums[1023];
}

__global__ __launch_bounds__(256) void scatter_kernel(
        const int* __restrict__ r0, const int* __restrict__ c0, const float* __restrict__ v0,
        const int* __restrict__ r1, const int* __restrict__ c1, const float* __restrict__ v1,
        int* __restrict__ cur0, int* __restrict__ cur1,
        int* __restrict__ sc0_, float* __restrict__ sv0_,
        int* __restrict__ sc1_, float* __restrict__ sv1_) {
    const int bid = blockIdx.x;
    const bool sB = bid >= (NE / 256);
    const int e = (sB ? bid - NE / 256 : bid) * 256 + threadIdx.x;
    const int* rows = sB ? r1 : r0;
    const int* cols = sB ? c1 : c0;
    const float* vals = sB ? v1 : v0;
    int* cur = sB ? cur1 : cur0;
    int* scols = sB ? sc1_ : sc0_;
    float* svals = sB ? sv1_ : sv0_;
    const int r = rows[e];
    const int p = atomicAdd(&cur[r], 1);
    scols[p] = cols[e];
    svals[p] = vals[e];
}

// ---------- per-row insertion sort of (col,val) by col ----------
// Pure reordering (fp32 reassociation only). Makes concurrent spmm blocks walk
// the column space in loose lockstep -> active gather footprint ~5 MB -> L2/L3 hits.
__global__ __launch_bounds__(256) void sort_kernel(const int* __restrict__ rp0,
                                                   int* __restrict__ sc0, float* __restrict__ sv0,
                                                   const int* __restrict__ rp1,
                                                   int* __restrict__ sc1, float* __restrict__ sv1) {
    const int id = blockIdx.x * 256 + threadIdx.x;
    if (id >= 2 * NN) return;
    const bool sB = id >= NN;
    const int n = sB ? id - NN : id;
    const int* rp = sB ? rp1 : rp0;
    int* sc = sB ? sc1 : sc0;
    float* sv = sB ? sv1 : sv0;
    const int e0 = rp[n], e1 = rp[n + 1];
    for (int i = e0 + 1; i < e1; i++) {
        const int c = sc[i];
        const float v = sv[i];
        int j = i - 1;
        while (j >= e0 && sc[j] > c) {
            sc[j + 1] = sc[j];
            sv[j + 1] = sv[j];
            j--;
        }
        sc[j + 1] = c;
        sv[j + 1] = v;
    }
}

// ---------- Wt[o][k] (bf16, k = m*66+d) with Chebyshev folding:
// out = (W0-W2-W4) x0 + W1 y1 + 2W2 y2 + W3 y3 + 2W4 y4   (y = pure A-gathers)
__global__ __launch_bounds__(256) void wprep_kernel(const float* __restrict__ weight,
                                                    ushort* __restrict__ Wt) {
    const int t = threadIdx.x;
    const int o = t & 63, rep = t >> 6;
    for (int kk = 0; kk < 88; kk++) {
        const int k = rep * 88 + kk;
        float v = 0.f;
        if (k < 330) {
            const int m = (int)(((long long)k * 63551) >> 22);   // k/66
            const int d = k - 66 * m;
            if (m == 0)
                v = weight[(d * 5 + 0) * 64 + o] - weight[(d * 5 + 2) * 64 + o]
                    - weight[(d * 5 + 4) * 64 + o];
            else if (m == 2)
                v = 2.f * weight[(d * 5 + 2) * 64 + o];
            else if (m == 4)
                v = 2.f * weight[(d * 5 + 4) * 64 + o];
            else
                v = weight[(d * 5 + m) * 64 + o];
        }
        uint uv = __float_as_uint(v);
        uv += 0x7fffu + ((uv >> 16) & 1u);
        Wt[o * 352 + k] = (ushort)(uv >> 16);
    }
}

// ---------- pure gather spmm, both supports in one dispatch ----------
__device__ __forceinline__ void acc8(float* a, float v, uint4 u) {
    a[0] = fmaf(v, bflo(u.x), a[0]); a[1] = fmaf(v, bfhi(u.x), a[1]);
    a[2] = fmaf(v, bflo(u.y), a[2]); a[3] = fmaf(v, bfhi(u.y), a[3]);
    a[4] = fmaf(v, bflo(u.z), a[4]); a[5] = fmaf(v, bfhi(u.z), a[5]);
    a[6] = fmaf(v, bflo(u.w), a[6]); a[7] = fmaf(v, bfhi(u.w), a[7]);
}
__device__ __forceinline__ uint4 pack8(const float* a) {
    uint4 r;
    r.x = packbf(a[0], a[1]); r.y = packbf(a[2], a[3]);
    r.z = packbf(a[4], a[5]); r.w = packbf(a[6], a[7]);
    return r;
}

__global__ __launch_bounds__(256) void spmm_kernel(
        const int* __restrict__ rpA, const int* __restrict__ scA, const float* __restrict__ svA,
        const uint* __restrict__ xA, uint* __restrict__ yA,
        const int* __restrict__ rpB, const int* __restrict__ scB, const float* __restrict__ svB,
        const uint* __restrict__ xB, uint* __restrict__ yB) {
    const int bid = blockIdx.x;
    const bool sB = bid >= NN;
    const int n = sB ? bid - NN : bid;
    const int* __restrict__ rp = sB ? rpB : rpA;
    const int* __restrict__ sc = sB ? scB : scA;
    const float* __restrict__ sv = sB ? svB : svA;
    const uint* __restrict__ x = sB ? xB : xA;
    uint* __restrict__ y = sB ? yB : yA;
    const int t = threadIdx.x;

    float acc[24];
#pragma unroll
    for (int i = 0; i < 24; i++) acc[i] = 0.f;

    const int e0 = rp[n], e1 = rp[n + 1];
    int e = e0;
    // 2-edge unroll: two independent gather chains in flight
    for (; e + 2 <= e1; e += 2) {
        const int cA = sc[e], cB = sc[e + 1];
        const float vA = sv[e], vB = sv[e + 1];
        const uint4* ra = (const uint4*)(x + (size_t)cA * ROWU);
        const uint4* rb = (const uint4*)(x + (size_t)cB * ROWU);
        const uint4 a0 = ra[t], a1 = ra[t + 256];
        const uint4 b0 = rb[t], b1 = rb[t + 256];
        acc8(acc + 0, vA, a0); acc8(acc + 8, vA, a1);
        acc8(acc + 0, vB, b0); acc8(acc + 8, vB, b1);
        if (t < 16) {   // tail chunks 512..527 (wave 0 only)
            const uint4 a2 = ra[512 + t];
            const uint4 b2 = rb[512 + t];
            acc8(acc + 16, vA, a2);
            acc8(acc + 16, vB, b2);
        }
    }
    if (e < e1) {
        const int cA = sc[e];
        const float vA = sv[e];
        const uint4* ra = (const uint4*)(x + (size_t)cA * ROWU);
        const uint4 a0 = ra[t], a1 = ra[t + 256];
        acc8(acc + 0, vA, a0); acc8(acc + 8, vA, a1);
        if (t < 16) {
            const uint4 a2 = ra[512 + t];
            acc8(acc + 16, vA, a2);
        }
    }

    uint4* yr = (uint4*)(y + (size_t)n * ROWU);
    yr[t] = pack8(acc + 0);
    yr[t + 256] = pack8(acc + 8);
    if (t < 16) yr[512 + t] = pack8(acc + 16);
}

// ---------- per-(node, b-half) MFMA GEMM: half-size LDS -> 2x blocks/CU ----------
// LDS Xt[b_local][k] : 32 rows, stride 360 ushorts (720 B) — same verified layout,
// b-range parameterized by blockIdx half. 23040 B LDS -> 6-7 blocks/CU.
__global__ __launch_bounds__(256) void gemm_kernel(const uint* __restrict__ p0,
                                                   const uint* __restrict__ p1,
                                                   const uint* __restrict__ p2,
                                                   const uint* __restrict__ p3,
                                                   const uint* __restrict__ p4,
                                                   const ushort* __restrict__ Wt,
                                                   const float* __restrict__ bias,
                                                   float* __restrict__ out) {
    __shared__ ushort Xt[32 * 360];
    const int bid = blockIdx.x;
    const int n = bid >> 1, half = bid & 1;
    const int t = threadIdx.x;

    // stage 5 half-rows (32 b's x 33 uints each) into Xt[b_local][m*66+d]
#pragma unroll
    for (int m = 0; m < 5; m++) {
        const uint* src = (m == 0) ? p0 : (m == 1) ? p1 : (m == 2) ? p2 : (m == 3) ? p3 : p4;
        src += (size_t)n * ROWU + half * 1056;
#pragma unroll
        for (int j = 0; j < 5; j++) {
            const int flat = 256 * j + t;          // < 1056
            if (flat < 1056) {
                const int b = (int)(((long long)flat * 127101) >> 22);  // flat/33
                const int i = flat - 33 * b;
                *(uint*)&Xt[b * 360 + m * 66 + 2 * i] = src[flat];
            }
        }
    }
    if (t < 32) {   // zero pad k in [330,360)
#pragma unroll
        for (int i = 0; i < 15; i++)
            *(uint*)&Xt[t * 360 + 330 + 2 * i] = 0u;
    }
    __syncthreads();

    const int w = t >> 6;        // wave -> o-tile
    const int l = t & 63;
    const int q = l >> 4;        // k-chunk quad
    const int r = l & 15;

    // A-operand (Wt) fragments: A[row 16w+r][k chunk q*8 + s*32]
    short8 afr[11];
#pragma unroll
    for (int s = 0; s < 11; s++)
        afr[s] = *(const short8*)&Wt[(16 * w + r) * 352 + s * 32 + q * 8];

    const float4 bv = *(const float4*)&bias[16 * w + 4 * q];

#pragma unroll
    for (int bt = 0; bt < 2; bt++) {
        f32x4 acc = {0.f, 0.f, 0.f, 0.f};
        const ushort* xrow = &Xt[(16 * bt + r) * 360];
#pragma unroll
        for (int s = 0; s < 11; s++) {
            const short8 bfr = *(const short8*)&xrow[s * 32 + q * 8];
            acc = __builtin_amdgcn_mfma_f32_16x16x32_bf16(afr[s], bfr, acc, 0, 0, 0);
        }
        // D: col = lane&15 -> b, row = q*4+reg -> o (consecutive o => float4 store)
        float4 res;
        res.x = acc[0] + bv.x;
        res.y = acc[1] + bv.y;
        res.z = acc[2] + bv.z;
        res.w = acc[3] + bv.w;
        const int bglob = 32 * half + 16 * bt + r;
        *(float4*)&out[(size_t)bglob * OUTSTRIDE + (size_t)n * 64 + 16 * w + 4 * q] = res;
    }
}

extern "C" void kernel_launch(void* const* d_in, const int* in_sizes, int n_in,
                              void* d_out, int out_size, void* d_ws, size_t ws_size,
                              hipStream_t stream) {
    const float* inputs = (const float*)d_in[0];
    const float* weight = (const float*)d_in[2];
    const float* biases = (const float*)d_in[3];
    const float* vals0  = (const float*)d_in[4];
    const float* vals1  = (const float*)d_in[5];
    const int*   rows0  = (const int*)d_in[6];
    const int*   cols0  = (const int*)d_in[7];
    const int*   rows1  = (const int*)d_in[8];
    const int*   cols1  = (const int*)d_in[9];
    float* out = (float*)d_out;

    // workspace: 5 bf16 X buffers (422.4 MB) + Wt + CSR (~3 MB) — unchanged layout
    const size_t SZX = (size_t)NN * ROWU;           // uints per buffer
    uint* x0  = (uint*)d_ws;
    uint* xa0 = x0 + SZX;
    uint* xb0 = xa0 + SZX;
    uint* xa1 = xb0 + SZX;
    uint* xb1 = xa1 + SZX;
    ushort* Wt = (ushort*)(xb1 + SZX);              // 64*352 ushorts
    int* cnt0 = (int*)(Wt + 64 * 352);
    int* cnt1 = cnt0 + NN;
    int* rp0  = cnt1 + NN;
    int* rp1  = rp0 + (NN + 1);
    int* cur0 = rp1 + (NN + 1);
    int* cur1 = cur0 + NN;
    int* sc0  = cur1 + NN;
    int* sc1  = sc0 + NE;
    float* sv0 = (float*)(sc1 + NE);
    float* sv1 = sv0 + NE;

    hipMemsetAsync(cnt0, 0, 2 * NN * sizeof(int), stream);
    transpose_kernel<<<NN, 256, 0, stream>>>(inputs, x0);

    hist_kernel<<<2 * (NE / 256), 256, 0, stream>>>(rows0, rows1, cnt0, cnt1);
    scan_kernel<<<2, 1024, 0, stream>>>(cnt0, rp0, cur0, cnt1, rp1, cur1);
    scatter_kernel<<<2 * (NE / 256), 256, 0, stream>>>(rows0, cols0, vals0,
                                                       rows1, cols1, vals1,
                                                       cur0, cur1, sc0, sv0, sc1, sv1);
    sort_kernel<<<(2 * NN + 255) / 256, 256, 0, stream>>>(rp0, sc0, sv0, rp1, sc1, sv1);
    wprep_kernel<<<1, 256, 0, stream>>>(weight, Wt);

    // pure gathers: y1 = A0 x0, y2 = A0 y1, y3 = A1 x0, y4 = A1 y3
    // (Chebyshev 2x / -x0 folded into Wt)
    spmm_kernel<<<2 * NN, 256, 0, stream>>>(rp0, sc0, sv0, x0, xa0,
                                            rp1, sc1, sv1, x0, xa1);
    spmm_kernel<<<2 * NN, 256, 0, stream>>>(rp0, sc0, sv0, xa0, xb0,
                                            rp1, sc1, sv1, xa1, xb1);

    gemm_kernel<<<2 * NN, 256, 0, stream>>>(x0, xa0, xb0, xa1, xb1, Wt, biases, out);
}

// Round 4
// 1440.829 us; speedup vs baseline: 1.0845x; 1.0845x over previous
//
#include <hip/hip_runtime.h>

#define NN 10000
#define NE 160000
#define ROWU 2112          // uints per node row (4224 bf16 = 66*64)
#define OUTSTRIDE 640000   // N*O floats per batch image

typedef unsigned int uint;
typedef unsigned short ushort;
typedef __attribute__((ext_vector_type(8))) short short8;
typedef __attribute__((ext_vector_type(4))) float f32x4;

__device__ __forceinline__ float bflo(uint u) { return __uint_as_float(u << 16); }
__device__ __forceinline__ float bfhi(uint u) { return __uint_as_float(u & 0xffff0000u); }
// RTNE pack of two fp32 -> packed bf16 pair
__device__ __forceinline__ uint packbf(float a, float b) {
    uint ua = __float_as_uint(a); ua += 0x7fffu + ((ua >> 16) & 1u);
    uint ub = __float_as_uint(b); ub += 0x7fffu + ((ub >> 16) & 1u);
    return (ua >> 16) | (ub & 0xffff0000u);
}

// ---------- x0[n][b*66+d] (bf16) = inputs[b][n*66+d] ----------
__global__ __launch_bounds__(256) void transpose_kernel(const float* __restrict__ in,
                                                        uint* __restrict__ x0) {
    const int n = blockIdx.x, t = threadIdx.x;
    const float* src = in + (size_t)n * 66;
    uint* dst = x0 + (size_t)n * ROWU;
#pragma unroll
    for (int j = 0; j < 9; j++) {
        const int ui = 256 * j + t;
        if (ui < ROWU) {
            const int idx = 2 * ui;                 // element index b*66+d (even, so no b-cross)
            const int b = (int)(((long long)idx * 63551) >> 22);   // idx/66
            const int d = idx - 66 * b;
            const float a0 = src[(size_t)b * 660000 + d];
            const float a1 = src[(size_t)b * 660000 + d + 1];
            dst[ui] = packbf(a0, a1);
        }
    }
}

// ---------- CSR build (both supports in one dispatch each) ----------
__global__ __launch_bounds__(256) void hist_kernel(const int* __restrict__ r0,
                                                   const int* __restrict__ r1,
                                                   int* __restrict__ c0,
                                                   int* __restrict__ c1) {
    const int bid = blockIdx.x;
    const bool sB = bid >= (NE / 256);
    const int e = (sB ? bid - NE / 256 : bid) * 256 + threadIdx.x;
    const int* rows = sB ? r1 : r0;
    int* cnt = sB ? c1 : c0;
    atomicAdd(&cnt[rows[e]], 1);
}

__global__ __launch_bounds__(1024) void scan_kernel(const int* __restrict__ c0,
                                                    int* __restrict__ rp0_, int* __restrict__ cur0_,
                                                    const int* __restrict__ c1,
                                                    int* __restrict__ rp1_, int* __restrict__ cur1_) {
    const int s = blockIdx.x;
    const int* cnt = s ? c1 : c0;
    int* rp  = s ? rp1_  : rp0_;
    int* cur = s ? cur1_ : cur0_;
    __shared__ int sums[1024];
    const int t = threadIdx.x;
    const int base = t * 10;
    int vals[10];
    int local = 0;
#pragma unroll
    for (int i = 0; i < 10; i++) {
        const int idx = base + i;
        const int v = (idx < NN) ? cnt[idx] : 0;
        vals[i] = local;
        local += v;
    }
    sums[t] = local;
    __syncthreads();
    for (int off = 1; off < 1024; off <<= 1) {
        const int v = (t >= off) ? sums[t - off] : 0;
        __syncthreads();
        sums[t] += v;
        __syncthreads();
    }
    const int excl = (t == 0) ? 0 : sums[t - 1];
#pragma unroll
    for (int i = 0; i < 10; i++) {
        const int idx = base + i;
        if (idx < NN) {
            const int v = excl + vals[i];
            rp[idx] = v;
            cur[idx] = v;
        }
    }
    if (t == 1023) rp[NN] = sums[1023];
}

__global__ __launch_bounds__(256) void scatter_kernel(
        const int* __restrict__ r0, const int* __restrict__ c0, const float* __restrict__ v0,
        const int* __restrict__ r1, const int* __restrict__ c1, const float* __restrict__ v1,
        int* __restrict__ cur0, int* __restrict__ cur1,
        int* __restrict__ sc0_, float* __restrict__ sv0_,
        int* __restrict__ sc1_, float* __restrict__ sv1_) {
    const int bid = blockIdx.x;
    const bool sB = bid >= (NE / 256);
    const int e = (sB ? bid - NE / 256 : bid) * 256 + threadIdx.x;
    const int* rows = sB ? r1 : r0;
    const int* cols = sB ? c1 : c0;
    const float* vals = sB ? v1 : v0;
    int* cur = sB ? cur1 : cur0;
    int* scols = sB ? sc1_ : sc0_;
    float* svals = sB ? sv1_ : sv0_;
    const int r = rows[e];
    const int p = atomicAdd(&cur[r], 1);
    scols[p] = cols[e];
    svals[p] = vals[e];
}

// ---------- Wt[o][k] (bf16, k = m*66+d) with Chebyshev folding:
// out = (W0-W2-W4) x0 + W1 y1 + 2W2 y2 + W3 y3 + 2W4 y4   (y = pure A-gathers)
__global__ __launch_bounds__(256) void wprep_kernel(const float* __restrict__ weight,
                                                    ushort* __restrict__ Wt) {
    const int t = threadIdx.x;
    const int o = t & 63, rep = t >> 6;
    for (int kk = 0; kk < 88; kk++) {
        const int k = rep * 88 + kk;
        float v = 0.f;
        if (k < 330) {
            const int m = (int)(((long long)k * 63551) >> 22);   // k/66
            const int d = k - 66 * m;
            if (m == 0)
                v = weight[(d * 5 + 0) * 64 + o] - weight[(d * 5 + 2) * 64 + o]
                    - weight[(d * 5 + 4) * 64 + o];
            else if (m == 2)
                v = 2.f * weight[(d * 5 + 2) * 64 + o];
            else if (m == 4)
                v = 2.f * weight[(d * 5 + 4) * 64 + o];
            else
                v = weight[(d * 5 + m) * 64 + o];
        }
        uint uv = __float_as_uint(v);
        uv += 0x7fffu + ((uv >> 16) & 1u);
        Wt[o * 352 + k] = (ushort)(uv >> 16);
    }
}

// ---------- pure gather spmm, both supports in one dispatch ----------
// XCD partition: g = bid%8 (empirical XCD round-robin). Support 0 -> XCDs 0-3,
// support 1 -> XCDs 4-7: each XCD touches exactly ONE source buffer (84.5 MB,
// was 169 MB in hop-2) and streams contiguous CSR/n-ranges.
__device__ __forceinline__ void acc8(float* a, float v, uint4 u) {
    a[0] = fmaf(v, bflo(u.x), a[0]); a[1] = fmaf(v, bfhi(u.x), a[1]);
    a[2] = fmaf(v, bflo(u.y), a[2]); a[3] = fmaf(v, bfhi(u.y), a[3]);
    a[4] = fmaf(v, bflo(u.z), a[4]); a[5] = fmaf(v, bfhi(u.z), a[5]);
    a[6] = fmaf(v, bflo(u.w), a[6]); a[7] = fmaf(v, bfhi(u.w), a[7]);
}
__device__ __forceinline__ uint4 pack8(const float* a) {
    uint4 r;
    r.x = packbf(a[0], a[1]); r.y = packbf(a[2], a[3]);
    r.z = packbf(a[4], a[5]); r.w = packbf(a[6], a[7]);
    return r;
}

__global__ __launch_bounds__(256) void spmm_kernel(
        const int* __restrict__ rpA, const int* __restrict__ scA, const float* __restrict__ svA,
        const uint* __restrict__ xA, uint* __restrict__ yA,
        const int* __restrict__ rpB, const int* __restrict__ scB, const float* __restrict__ svB,
        const uint* __restrict__ xB, uint* __restrict__ yB) {
    const int bid = blockIdx.x;                 // 2*NN = 20000 blocks
    const int g = bid & 7, i = bid >> 3;        // g -> XCD (round-robin heuristic), i in [0,2500)
    const bool sB = g >= 4;
    const int n = (g & 3) * 2500 + i;           // support covers n in [0,10000) exactly once
    const int* __restrict__ rp = sB ? rpB : rpA;
    const int* __restrict__ sc = sB ? scB : scA;
    const float* __restrict__ sv = sB ? svB : svA;
    const uint* __restrict__ x = sB ? xB : xA;
    uint* __restrict__ y = sB ? yB : yA;
    const int t = threadIdx.x;

    float acc[24];
#pragma unroll
    for (int i2 = 0; i2 < 24; i2++) acc[i2] = 0.f;

    const int e0 = rp[n], e1 = rp[n + 1];
    int e = e0;
    // 4-edge unroll: 8-12 independent uint4 gathers in flight per wave
    for (; e + 4 <= e1; e += 4) {
        const int c0 = sc[e], c1 = sc[e + 1], c2 = sc[e + 2], c3 = sc[e + 3];
        const float v0 = sv[e], v1 = sv[e + 1], v2 = sv[e + 2], v3 = sv[e + 3];
        const uint4* r0 = (const uint4*)(x + (size_t)c0 * ROWU);
        const uint4* r1 = (const uint4*)(x + (size_t)c1 * ROWU);
        const uint4* r2 = (const uint4*)(x + (size_t)c2 * ROWU);
        const uint4* r3 = (const uint4*)(x + (size_t)c3 * ROWU);
        const uint4 a0 = r0[t], a1 = r0[t + 256];
        const uint4 b0 = r1[t], b1 = r1[t + 256];
        const uint4 c0v = r2[t], c1v = r2[t + 256];
        const uint4 d0 = r3[t], d1 = r3[t + 256];
        uint4 at = {0, 0, 0, 0}, bt = {0, 0, 0, 0}, ct = {0, 0, 0, 0}, dt = {0, 0, 0, 0};
        if (t < 16) {
            at = r0[512 + t]; bt = r1[512 + t];
            ct = r2[512 + t]; dt = r3[512 + t];
        }
        acc8(acc + 0, v0, a0); acc8(acc + 8, v0, a1);
        acc8(acc + 0, v1, b0); acc8(acc + 8, v1, b1);
        acc8(acc + 0, v2, c0v); acc8(acc + 8, v2, c1v);
        acc8(acc + 0, v3, d0); acc8(acc + 8, v3, d1);
        if (t < 16) {
            acc8(acc + 16, v0, at); acc8(acc + 16, v1, bt);
            acc8(acc + 16, v2, ct); acc8(acc + 16, v3, dt);
        }
    }
    for (; e + 2 <= e1; e += 2) {
        const int cA = sc[e], cB = sc[e + 1];
        const float vA = sv[e], vB = sv[e + 1];
        const uint4* ra = (const uint4*)(x + (size_t)cA * ROWU);
        const uint4* rb = (const uint4*)(x + (size_t)cB * ROWU);
        const uint4 a0 = ra[t], a1 = ra[t + 256];
        const uint4 b0 = rb[t], b1 = rb[t + 256];
        acc8(acc + 0, vA, a0); acc8(acc + 8, vA, a1);
        acc8(acc + 0, vB, b0); acc8(acc + 8, vB, b1);
        if (t < 16) {
            const uint4 a2 = ra[512 + t];
            const uint4 b2 = rb[512 + t];
            acc8(acc + 16, vA, a2);
            acc8(acc + 16, vB, b2);
        }
    }
    if (e < e1) {
        const int cA = sc[e];
        const float vA = sv[e];
        const uint4* ra = (const uint4*)(x + (size_t)cA * ROWU);
        const uint4 a0 = ra[t], a1 = ra[t + 256];
        acc8(acc + 0, vA, a0); acc8(acc + 8, vA, a1);
        if (t < 16) {
            const uint4 a2 = ra[512 + t];
            acc8(acc + 16, vA, a2);
        }
    }

    uint4* yr = (uint4*)(y + (size_t)n * ROWU);
    yr[t] = pack8(acc + 0);
    yr[t + 256] = pack8(acc + 8);
    if (t < 16) yr[512 + t] = pack8(acc + 16);
}

// ---------- per-(node, b-half) MFMA GEMM: half-size LDS -> 2x blocks/CU ----------
// LDS Xt[b_local][k] : 32 rows, stride 360 ushorts (720 B) — same verified layout,
// b-range parameterized by blockIdx half. 23040 B LDS -> 6-7 blocks/CU.
__global__ __launch_bounds__(256) void gemm_kernel(const uint* __restrict__ p0,
                                                   const uint* __restrict__ p1,
                                                   const uint* __restrict__ p2,
                                                   const uint* __restrict__ p3,
                                                   const uint* __restrict__ p4,
                                                   const ushort* __restrict__ Wt,
                                                   const float* __restrict__ bias,
                                                   float* __restrict__ out) {
    __shared__ ushort Xt[32 * 360];
    const int bid = blockIdx.x;
    const int n = bid >> 1, half = bid & 1;
    const int t = threadIdx.x;

    // stage 5 half-rows (32 b's x 33 uints each) into Xt[b_local][m*66+d]
#pragma unroll
    for (int m = 0; m < 5; m++) {
        const uint* src = (m == 0) ? p0 : (m == 1) ? p1 : (m == 2) ? p2 : (m == 3) ? p3 : p4;
        src += (size_t)n * ROWU + half * 1056;
#pragma unroll
        for (int j = 0; j < 5; j++) {
            const int flat = 256 * j + t;          // < 1056
            if (flat < 1056) {
                const int b = (int)(((long long)flat * 127101) >> 22);  // flat/33
                const int i = flat - 33 * b;
                *(uint*)&Xt[b * 360 + m * 66 + 2 * i] = src[flat];
            }
        }
    }
    if (t < 32) {   // zero pad k in [330,360)
#pragma unroll
        for (int i = 0; i < 15; i++)
            *(uint*)&Xt[t * 360 + 330 + 2 * i] = 0u;
    }
    __syncthreads();

    const int w = t >> 6;        // wave -> o-tile
    const int l = t & 63;
    const int q = l >> 4;        // k-chunk quad
    const int r = l & 15;

    // A-operand (Wt) fragments: A[row 16w+r][k chunk q*8 + s*32]
    short8 afr[11];
#pragma unroll
    for (int s = 0; s < 11; s++)
        afr[s] = *(const short8*)&Wt[(16 * w + r) * 352 + s * 32 + q * 8];

    const float4 bv = *(const float4*)&bias[16 * w + 4 * q];

#pragma unroll
    for (int bt = 0; bt < 2; bt++) {
        f32x4 acc = {0.f, 0.f, 0.f, 0.f};
        const ushort* xrow = &Xt[(16 * bt + r) * 360];
#pragma unroll
        for (int s = 0; s < 11; s++) {
            const short8 bfr = *(const short8*)&xrow[s * 32 + q * 8];
            acc = __builtin_amdgcn_mfma_f32_16x16x32_bf16(afr[s], bfr, acc, 0, 0, 0);
        }
        // D: col = lane&15 -> b, row = q*4+reg -> o (consecutive o => float4 store)
        float4 res;
        res.x = acc[0] + bv.x;
        res.y = acc[1] + bv.y;
        res.z = acc[2] + bv.z;
        res.w = acc[3] + bv.w;
        const int bglob = 32 * half + 16 * bt + r;
        *(float4*)&out[(size_t)bglob * OUTSTRIDE + (size_t)n * 64 + 16 * w + 4 * q] = res;
    }
}

extern "C" void kernel_launch(void* const* d_in, const int* in_sizes, int n_in,
                              void* d_out, int out_size, void* d_ws, size_t ws_size,
                              hipStream_t stream) {
    const float* inputs = (const float*)d_in[0];
    const float* weight = (const float*)d_in[2];
    const float* biases = (const float*)d_in[3];
    const float* vals0  = (const float*)d_in[4];
    const float* vals1  = (const float*)d_in[5];
    const int*   rows0  = (const int*)d_in[6];
    const int*   cols0  = (const int*)d_in[7];
    const int*   rows1  = (const int*)d_in[8];
    const int*   cols1  = (const int*)d_in[9];
    float* out = (float*)d_out;

    // workspace: 5 bf16 X buffers (422.4 MB) + Wt + CSR (~3 MB) — unchanged layout
    const size_t SZX = (size_t)NN * ROWU;           // uints per buffer
    uint* x0  = (uint*)d_ws;
    uint* xa0 = x0 + SZX;
    uint* xb0 = xa0 + SZX;
    uint* xa1 = xb0 + SZX;
    uint* xb1 = xa1 + SZX;
    ushort* Wt = (ushort*)(xb1 + SZX);              // 64*352 ushorts
    int* cnt0 = (int*)(Wt + 64 * 352);
    int* cnt1 = cnt0 + NN;
    int* rp0  = cnt1 + NN;
    int* rp1  = rp0 + (NN + 1);
    int* cur0 = rp1 + (NN + 1);
    int* cur1 = cur0 + NN;
    int* sc0  = cur1 + NN;
    int* sc1  = sc0 + NE;
    float* sv0 = (float*)(sc1 + NE);
    float* sv1 = sv0 + NE;

    hipMemsetAsync(cnt0, 0, 2 * NN * sizeof(int), stream);
    transpose_kernel<<<NN, 256, 0, stream>>>(inputs, x0);

    hist_kernel<<<2 * (NE / 256), 256, 0, stream>>>(rows0, rows1, cnt0, cnt1);
    scan_kernel<<<2, 1024, 0, stream>>>(cnt0, rp0, cur0, cnt1, rp1, cur1);
    scatter_kernel<<<2 * (NE / 256), 256, 0, stream>>>(rows0, cols0, vals0,
                                                       rows1, cols1, vals1,
                                                       cur0, cur1, sc0, sv0, sc1, sv1);
    wprep_kernel<<<1, 256, 0, stream>>>(weight, Wt);

    // pure gathers: y1 = A0 x0, y2 = A0 y1, y3 = A1 x0, y4 = A1 y3
    // (Chebyshev 2x / -x0 folded into Wt)
    spmm_kernel<<<2 * NN, 256, 0, stream>>>(rp0, sc0, sv0, x0, xa0,
                                            rp1, sc1, sv1, x0, xa1);
    spmm_kernel<<<2 * NN, 256, 0, stream>>>(rp0, sc0, sv0, xa0, xb0,
                                            rp1, sc1, sv1, xa1, xb1);

    gemm_kernel<<<2 * NN, 256, 0, stream>>>(x0, xa0, xb0, xa1, xb1, Wt, biases, out);
}